// Round 12
// baseline (73.475 us; speedup 1.0000x reference)
//
#include <hip/hip_runtime.h>

#define BB 16
#define CIN 256
#define COUT 128
#define EE 512
#define HH 64
#define WW 64
#define HP 66   // padded spatial dim
#define NCG 16  // CIN/16 chunks of 16 i8

typedef int v4i __attribute__((ext_vector_type(4)));
typedef int v16i __attribute__((ext_vector_type(16)));

// ws layout (bytes):
//   bias1 [16][256] f32 @ 0        (16384)
//   bias2 [16][128] f32 @ 16384    (8192)
//   bias3 [16][128] f32 @ 24576    (8192)
//   A     [128] f32     @ 33280    (512)
//   B0    [128] f32     @ 33792    (512)
//   Wt2   [9][16][128]x16B @ 34304 (294912)    (tap, c-chunk, o)
//   S2    [16][66][16][66]x16B @ 329216 (17842176)  (b, row, c-chunk, col)

__global__ __launch_bounds__(256) void prep2_k(
    const float* __restrict__ emb,
    const float* __restrict__ m1w, const float* __restrict__ m1b,
    const float* __restrict__ m2w, const float* __restrict__ m2b,
    const float* __restrict__ m3w, const float* __restrict__ m3b,
    const float* __restrict__ conv_w, const float* __restrict__ conv_b,
    const float* __restrict__ bn_g, const float* __restrict__ bn_b,
    const float* __restrict__ bn_m, const float* __restrict__ bn_v,
    float* __restrict__ bias1, float* __restrict__ bias2, float* __restrict__ bias3,
    float* __restrict__ A, float* __restrict__ B0,
    signed char* __restrict__ Wt)
{
    int bid = blockIdx.x;
    int tid = threadIdx.x;
    __shared__ float red[256];
    if (bid < 128) {
        int b = bid >> 3;
        int chunk = bid & 7;
        __shared__ float se[EE];
        {
            float v0 = emb[b * EE + tid];
            float v1 = emb[b * EE + tid + 256];
            se[tid] = v0 / (1.0f + __expf(-v0));
            se[tid + 256] = v1 / (1.0f + __expf(-v1));
        }
        __syncthreads();
        int cl = tid & 63;
        int ks = tid >> 6;
        const float* W;
        const float* Bv;
        float* dst;
        int c0;
        if (chunk < 4)      { c0 = chunk * 64;       W = m1w; Bv = m1b; dst = bias1 + b * CIN + c0; }
        else if (chunk < 6) { c0 = (chunk - 4) * 64; W = m2w; Bv = m2b; dst = bias2 + b * COUT + c0; }
        else                { c0 = (chunk - 6) * 64; W = m3w; Bv = m3b; dst = bias3 + b * COUT + c0; }
        const float4* w4 = (const float4*)(W + (size_t)(c0 + cl) * EE + ks * 128);
        const float* sp = &se[ks * 128];
        float acc = 0.f;
        #pragma unroll
        for (int e4 = 0; e4 < 32; ++e4) {
            float4 v = w4[e4];
            acc += sp[e4 * 4 + 0] * v.x + sp[e4 * 4 + 1] * v.y +
                   sp[e4 * 4 + 2] * v.z + sp[e4 * 4 + 3] * v.w;
        }
        red[tid] = acc;
        __syncthreads();
        if (ks == 0)
            dst[cl] = red[cl] + red[cl + 64] + red[cl + 128] + red[cl + 192] + Bv[c0 + cl];
    } else {
        int o = bid - 128;
        int c = tid;
        float wv[9];
        float asum = 0.f;
        const float* wp = conv_w + ((size_t)o * CIN + c) * 9;
        #pragma unroll
        for (int k = 0; k < 9; ++k) {
            float v = wp[k];
            wv[k] = v;
            asum += fabsf(v);
        }
        #pragma unroll
        for (int k = 0; k < 9; ++k)
            Wt[(((size_t)k * NCG + (c >> 4)) * COUT + o) * 16 + (c & 15)] =
                (wv[k] > 0.f) ? (signed char)1 : (signed char)-1;
        red[tid] = asum;
        __syncthreads();
        for (int s = 128; s > 0; s >>= 1) {
            if (tid < s) red[tid] += red[tid + s];
            __syncthreads();
        }
        if (tid == 0) {
            float sc = red[0] * (1.0f / 2304.0f);
            float inv = bn_g[o] * rsqrtf(bn_v[o] + 1e-5f);
            A[o] = sc * inv;
            B0[o] = (conv_b[o] - bn_m[o]) * inv + bn_b[o];
        }
    }
}

// 1024 blocks (b*64+h), 256 threads = 64 w x 4 q-groups; q handles 4 c-chunks.
__global__ __launch_bounds__(256) void sign_k(
    const float* __restrict__ x, const float* __restrict__ bias1,
    signed char* __restrict__ S)
{
    __shared__ float sb[CIN];
    int bid = blockIdx.x;
    int b = bid >> 6;
    int h = bid & 63;
    int tid = threadIdx.x;

    // halo zeroing: 16 b * 260 ring cells * 16 cg = 66560 16-B chunks
    if (bid < 260) {
        int hidx = bid * 256 + tid;   // exactly 260*256 = 66560
        int cellg = hidx >> 4;
        int cg = hidx & 15;
        int b2 = cellg / 260;
        int rem = cellg % 260;
        int r, col;
        if (rem < 66)       { r = 0;  col = rem; }
        else if (rem < 132) { r = 65; col = rem - 66; }
        else                { int c2 = rem - 132; r = 1 + (c2 >> 1); col = (c2 & 1) * 65; }
        int4 z = make_int4(0, 0, 0, 0);
        *(int4*)(S + ((((size_t)b2 * HP + r) * NCG + cg) * HP + col) * 16) = z;
    }

    sb[tid] = bias1[b * CIN + tid];
    __syncthreads();

    int w = tid & 63;
    int q = tid >> 6;
    const float* xp = x + (size_t)b * CIN * (HH * WW) + (size_t)h * WW + w;
    #pragma unroll
    for (int st = 0; st < 4; ++st) {
        int cg = q * 4 + st;
        unsigned int pk0 = 0, pk1 = 0, pk2 = 0, pk3 = 0;
        #pragma unroll
        for (int j = 0; j < 4; ++j) {
            int c = cg * 16 + j;
            float t0 = xp[(size_t)(c +  0) * (HH * WW)] + sb[c +  0];
            float t1 = xp[(size_t)(c +  4) * (HH * WW)] + sb[c +  4];
            float t2 = xp[(size_t)(c +  8) * (HH * WW)] + sb[c +  8];
            float t3 = xp[(size_t)(c + 12) * (HH * WW)] + sb[c + 12];
            pk0 |= (t0 > 0.f ? 0x01u : 0xFFu) << (8 * j);
            pk1 |= (t1 > 0.f ? 0x01u : 0xFFu) << (8 * j);
            pk2 |= (t2 > 0.f ? 0x01u : 0xFFu) << (8 * j);
            pk3 |= (t3 > 0.f ? 0x01u : 0xFFu) << (8 * j);
        }
        int4 val = make_int4((int)pk0, (int)pk1, (int)pk2, (int)pk3);
        *(int4*)(S + ((((size_t)b * HP + (h + 1)) * NCG + cg) * HP + (w + 1)) * 16) = val;
    }
}

// 1024 blocks (b*64+h), 256 threads = 4 waves = (omg in 2) x (kg in 2).
// Each wave: 2x2 grid of 32x32 C-tiles (o = omg*64..+63, all 64 px), over
// half of K (kg). 1 KB of operand loads per MFMA (vs 1.5 in R11). Partials
// combined via LDS; epilogue split across all 4 waves.
__global__ __launch_bounds__(256, 4) void main2_k(
    const signed char* __restrict__ Wt,    // [9][16][128]x16B
    const signed char* __restrict__ S,     // [16][66][16][66]x16B
    const float* __restrict__ x,
    const float* __restrict__ A, const float* __restrict__ B0,
    const float* __restrict__ bias2, const float* __restrict__ bias3,
    const float* __restrict__ prelu_a,
    float* __restrict__ out)
{
    __shared__ int lacc[2][64][65];    // 33280 B
    int bid = blockIdx.x;
    int b = bid >> 6;
    int h = bid & 63;
    int tid = threadIdx.x;
    int lane = tid & 63;
    int wid = tid >> 6;
    int omg = wid & 1;
    int kg = wid >> 1;
    int lr = lane & 31;
    int lk = lane >> 5;

    v16i acc00 = {}, acc01 = {}, acc10 = {}, acc11 = {};

    const signed char* ap = Wt + ((size_t)lk * COUT + omg * 64 + lr) * 16;
    const signed char* bp = S + ((((size_t)b * HP + h) * NCG + lk) * HP + lr) * 16;

#define KSTEP(t, ck) { \
    v4i a0 = *(const v4i*)(ap + (((size_t)(t) * NCG + (ck) * 2) * COUT      ) * 16); \
    v4i a1 = *(const v4i*)(ap + (((size_t)(t) * NCG + (ck) * 2) * COUT + 32 ) * 16); \
    v4i b0 = *(const v4i*)(bp + ((((size_t)((t) / 3) * NCG + (ck) * 2) * HP) + ((t) % 3)      ) * 16); \
    v4i b1 = *(const v4i*)(bp + ((((size_t)((t) / 3) * NCG + (ck) * 2) * HP) + ((t) % 3) + 32 ) * 16); \
    acc00 = __builtin_amdgcn_mfma_i32_32x32x32_i8(a0, b0, acc00, 0, 0, 0); \
    acc01 = __builtin_amdgcn_mfma_i32_32x32x32_i8(a0, b1, acc01, 0, 0, 0); \
    acc10 = __builtin_amdgcn_mfma_i32_32x32x32_i8(a1, b0, acc10, 0, 0, 0); \
    acc11 = __builtin_amdgcn_mfma_i32_32x32x32_i8(a1, b1, acc11, 0, 0, 0); \
}
#define KROW(t) KSTEP(t,0) KSTEP(t,1) KSTEP(t,2) KSTEP(t,3) KSTEP(t,4) KSTEP(t,5) KSTEP(t,6) KSTEP(t,7)

    if (kg == 0) {
        KROW(0) KROW(1) KROW(2) KROW(3)
        KSTEP(4,0) KSTEP(4,1) KSTEP(4,2) KSTEP(4,3)
    } else {
        KSTEP(4,4) KSTEP(4,5) KSTEP(4,6) KSTEP(4,7)
        KROW(5) KROW(6) KROW(7) KROW(8)
    }
#undef KROW
#undef KSTEP

    // combine partials: kg=1 writes, kg=0 adds and writes back final
    if (kg == 1) {
        int* lp = &lacc[omg][lane][0];
        #pragma unroll
        for (int g = 0; g < 16; ++g) {
            lp[g]      = acc00[g];
            lp[16 + g] = acc01[g];
            lp[32 + g] = acc10[g];
            lp[48 + g] = acc11[g];
        }
    }
    __syncthreads();
    if (kg == 0) {
        int* lp = &lacc[omg][lane][0];
        #pragma unroll
        for (int g = 0; g < 16; ++g) {
            lp[g]      += acc00[g];
            lp[16 + g] += acc01[g];
            lp[32 + g] += acc10[g];
            lp[48 + g] += acc11[g];
        }
    }
    __syncthreads();

    // epilogue: wave (omg,kg) handles o in [omg*64, +64), w in [kg*32, +32)
    const int* lp = &lacc[omg][lane][0];
    #pragma unroll
    for (int i = 0; i < 2; ++i) {
        #pragma unroll
        for (int g = 0; g < 16; ++g) {
            int v = lp[i * 32 + kg * 16 + g];
            int o = omg * 64 + i * 32 + (g & 3) + 8 * (g >> 2) + 4 * lk;
            int w = kg * 32 + lr;
            float Ao = A[o], B0o = B0[o];
            float cv = (float)v * Ao + B0o;
            const float* xr = x + ((size_t)(b * CIN + 2 * o)) * (HH * WW) + (size_t)h * WW;
            float r0 = xr[w], r1 = xr[HH * WW + w];
            float tv = cv + 0.5f * (r0 + r1) + bias2[b * COUT + o];
            tv = tv > 0.f ? tv : prelu_a[o] * tv;
            out[((size_t)(b * COUT + o)) * (HH * WW) + (size_t)h * WW + w] = tv + bias3[b * COUT + o];
        }
    }
}

extern "C" void kernel_launch(void* const* d_in, const int* in_sizes, int n_in,
                              void* d_out, int out_size, void* d_ws, size_t ws_size,
                              hipStream_t stream) {
    const float* x      = (const float*)d_in[0];
    const float* emb    = (const float*)d_in[1];
    const float* m1w    = (const float*)d_in[2];
    const float* m1b    = (const float*)d_in[3];
    const float* conv_w = (const float*)d_in[4];
    const float* conv_b = (const float*)d_in[5];
    const float* bn_g   = (const float*)d_in[6];
    const float* bn_b   = (const float*)d_in[7];
    const float* bn_m   = (const float*)d_in[8];
    const float* bn_v   = (const float*)d_in[9];
    const float* m2w    = (const float*)d_in[10];
    const float* m2b    = (const float*)d_in[11];
    const float* pa     = (const float*)d_in[12];
    const float* m3w    = (const float*)d_in[13];
    const float* m3b    = (const float*)d_in[14];
    float* out = (float*)d_out;

    char* ws = (char*)d_ws;
    float* bias1 = (float*)(ws + 0);
    float* bias2 = (float*)(ws + 16384);
    float* bias3 = (float*)(ws + 24576);
    float* Aarr  = (float*)(ws + 33280);
    float* B0arr = (float*)(ws + 33792);
    signed char* Wt = (signed char*)(ws + 34304);
    signed char* S  = (signed char*)(ws + 329216);

    prep2_k<<<256, 256, 0, stream>>>(emb, m1w, m1b, m2w, m2b, m3w, m3b,
                                     conv_w, conv_b, bn_g, bn_b, bn_m, bn_v,
                                     bias1, bias2, bias3, Aarr, B0arr, Wt);
    sign_k<<<BB * HH, 256, 0, stream>>>(x, bias1, S);
    main2_k<<<BB * HH, 256, 0, stream>>>(Wt, S, x, Aarr, B0arr,
                                         bias2, bias3, pa, out);
}

// Round 13
// 66.139 us; speedup vs baseline: 1.1109x; 1.1109x over previous
//
#include <hip/hip_runtime.h>

#define BB 16
#define CIN 256
#define COUT 128
#define EE 512
#define HH 64
#define WW 64
#define HP 66   // padded spatial dim
#define NCG 16  // CIN/16 chunks of 16 i8

typedef int v4i __attribute__((ext_vector_type(4)));
typedef int v16i __attribute__((ext_vector_type(16)));

// ws layout (bytes):
//   bias1 [16][256] f32 @ 0        (16384)
//   bias2 [16][128] f32 @ 16384    (8192)
//   bias3 [16][128] f32 @ 24576    (8192)
//   A     [128] f32     @ 33280    (512)
//   B0    [128] f32     @ 33792    (512)
//   Wt2   [9][16][128]x16B @ 34304 (294912)    (tap, c-chunk, o)
//   S2    [16][66][16][66]x16B @ 329216 (17842176)  (b, row, c-chunk, col)

__global__ __launch_bounds__(256) void prep2_k(
    const float* __restrict__ emb,
    const float* __restrict__ m1w, const float* __restrict__ m1b,
    const float* __restrict__ m2w, const float* __restrict__ m2b,
    const float* __restrict__ m3w, const float* __restrict__ m3b,
    const float* __restrict__ conv_w, const float* __restrict__ conv_b,
    const float* __restrict__ bn_g, const float* __restrict__ bn_b,
    const float* __restrict__ bn_m, const float* __restrict__ bn_v,
    float* __restrict__ bias1, float* __restrict__ bias2, float* __restrict__ bias3,
    float* __restrict__ A, float* __restrict__ B0,
    signed char* __restrict__ Wt)
{
    int bid = blockIdx.x;
    int tid = threadIdx.x;
    __shared__ float red[256];
    if (bid < 128) {
        int b = bid >> 3;
        int chunk = bid & 7;
        __shared__ float se[EE];
        {
            float v0 = emb[b * EE + tid];
            float v1 = emb[b * EE + tid + 256];
            se[tid] = v0 / (1.0f + __expf(-v0));
            se[tid + 256] = v1 / (1.0f + __expf(-v1));
        }
        __syncthreads();
        int cl = tid & 63;
        int ks = tid >> 6;
        const float* W;
        const float* Bv;
        float* dst;
        int c0;
        if (chunk < 4)      { c0 = chunk * 64;       W = m1w; Bv = m1b; dst = bias1 + b * CIN + c0; }
        else if (chunk < 6) { c0 = (chunk - 4) * 64; W = m2w; Bv = m2b; dst = bias2 + b * COUT + c0; }
        else                { c0 = (chunk - 6) * 64; W = m3w; Bv = m3b; dst = bias3 + b * COUT + c0; }
        const float4* w4 = (const float4*)(W + (size_t)(c0 + cl) * EE + ks * 128);
        const float* sp = &se[ks * 128];
        float acc = 0.f;
        #pragma unroll
        for (int e4 = 0; e4 < 32; ++e4) {
            float4 v = w4[e4];
            acc += sp[e4 * 4 + 0] * v.x + sp[e4 * 4 + 1] * v.y +
                   sp[e4 * 4 + 2] * v.z + sp[e4 * 4 + 3] * v.w;
        }
        red[tid] = acc;
        __syncthreads();
        if (ks == 0)
            dst[cl] = red[cl] + red[cl + 64] + red[cl + 128] + red[cl + 192] + Bv[c0 + cl];
    } else {
        int o = bid - 128;
        int c = tid;
        float wv[9];
        float asum = 0.f;
        const float* wp = conv_w + ((size_t)o * CIN + c) * 9;
        #pragma unroll
        for (int k = 0; k < 9; ++k) {
            float v = wp[k];
            wv[k] = v;
            asum += fabsf(v);
        }
        #pragma unroll
        for (int k = 0; k < 9; ++k)
            Wt[(((size_t)k * NCG + (c >> 4)) * COUT + o) * 16 + (c & 15)] =
                (wv[k] > 0.f) ? (signed char)1 : (signed char)-1;
        red[tid] = asum;
        __syncthreads();
        for (int s = 128; s > 0; s >>= 1) {
            if (tid < s) red[tid] += red[tid + s];
            __syncthreads();
        }
        if (tid == 0) {
            float sc = red[0] * (1.0f / 2304.0f);
            float inv = bn_g[o] * rsqrtf(bn_v[o] + 1e-5f);
            A[o] = sc * inv;
            B0[o] = (conv_b[o] - bn_m[o]) * inv + bn_b[o];
        }
    }
}

// 1024 blocks (b*64+h), 256 threads = 64 w x 4 q-groups; q handles 4 c-chunks.
__global__ __launch_bounds__(256) void sign_k(
    const float* __restrict__ x, const float* __restrict__ bias1,
    signed char* __restrict__ S)
{
    __shared__ float sb[CIN];
    int bid = blockIdx.x;
    int b = bid >> 6;
    int h = bid & 63;
    int tid = threadIdx.x;

    // halo zeroing: 16 b * 260 ring cells * 16 cg = 66560 16-B chunks
    if (bid < 260) {
        int hidx = bid * 256 + tid;   // exactly 260*256 = 66560
        int cellg = hidx >> 4;
        int cg = hidx & 15;
        int b2 = cellg / 260;
        int rem = cellg % 260;
        int r, col;
        if (rem < 66)       { r = 0;  col = rem; }
        else if (rem < 132) { r = 65; col = rem - 66; }
        else                { int c2 = rem - 132; r = 1 + (c2 >> 1); col = (c2 & 1) * 65; }
        int4 z = make_int4(0, 0, 0, 0);
        *(int4*)(S + ((((size_t)b2 * HP + r) * NCG + cg) * HP + col) * 16) = z;
    }

    sb[tid] = bias1[b * CIN + tid];
    __syncthreads();

    int w = tid & 63;
    int q = tid >> 6;
    const float* xp = x + (size_t)b * CIN * (HH * WW) + (size_t)h * WW + w;
    #pragma unroll
    for (int st = 0; st < 4; ++st) {
        int cg = q * 4 + st;
        unsigned int pk0 = 0, pk1 = 0, pk2 = 0, pk3 = 0;
        #pragma unroll
        for (int j = 0; j < 4; ++j) {
            int c = cg * 16 + j;
            float t0 = xp[(size_t)(c +  0) * (HH * WW)] + sb[c +  0];
            float t1 = xp[(size_t)(c +  4) * (HH * WW)] + sb[c +  4];
            float t2 = xp[(size_t)(c +  8) * (HH * WW)] + sb[c +  8];
            float t3 = xp[(size_t)(c + 12) * (HH * WW)] + sb[c + 12];
            pk0 |= (t0 > 0.f ? 0x01u : 0xFFu) << (8 * j);
            pk1 |= (t1 > 0.f ? 0x01u : 0xFFu) << (8 * j);
            pk2 |= (t2 > 0.f ? 0x01u : 0xFFu) << (8 * j);
            pk3 |= (t3 > 0.f ? 0x01u : 0xFFu) << (8 * j);
        }
        int4 val = make_int4((int)pk0, (int)pk1, (int)pk2, (int)pk3);
        *(int4*)(S + ((((size_t)b * HP + (h + 1)) * NCG + cg) * HP + (w + 1)) * 16) = val;
    }
}

// 1024 blocks (b*64+h), 256 threads = 4 waves (om = 32-o tile) — R11
// structure, plus: the 3 S-rows (shared identically by all 4 waves) are
// staged once into LDS (50688 B, contiguous in global), and B fragments
// come from conflict-free ds_read_b128 instead of 4x-redundant global loads.
__global__ __launch_bounds__(256, 3) void main2_k(
    const signed char* __restrict__ Wt,    // [9][16][128]x16B
    const signed char* __restrict__ S,     // [16][66][16][66]x16B
    const float* __restrict__ x,
    const float* __restrict__ A, const float* __restrict__ B0,
    const float* __restrict__ bias2, const float* __restrict__ bias3,
    const float* __restrict__ prelu_a,
    float* __restrict__ out)
{
    __shared__ v4i Sl[3 * NCG * HP];   // 50688 B
    int bid = blockIdx.x;
    int b = bid >> 6;
    int h = bid & 63;
    int tid = threadIdx.x;
    int l = tid & 63;
    int om = tid >> 6;       // wave-uniform o-tile
    int lr = l & 31;
    int lk = l >> 5;

    // stage rows h..h+2 (contiguous 50688 B in S)
    {
        const v4i* src = (const v4i*)(S + (((size_t)b * HP + h) * NCG) * (size_t)HP * 16);
        #pragma unroll
        for (int i = 0; i < 13; ++i) {
            int idx = tid + i * 256;
            if (idx < 3 * NCG * HP) Sl[idx] = src[idx];
        }
    }
    __syncthreads();

    v16i acc0 = {};
    v16i acc1 = {};

    const signed char* abase = Wt + ((size_t)lk * COUT + om * 32 + lr) * 16;

    #pragma unroll
    for (int t = 0; t < 9; ++t) {
        const int r = t / 3, dw = t % 3;
        const signed char* ap = abase + (size_t)t * NCG * COUT * 16;
        const v4i* bl = &Sl[(r * NCG + lk) * HP + dw + lr];
        #pragma unroll
        for (int ck = 0; ck < 8; ++ck) {
            v4i a  = *(const v4i*)(ap + (size_t)ck * 2 * COUT * 16);
            v4i b0 = bl[ck * 2 * HP];
            v4i b1 = bl[ck * 2 * HP + 32];
            acc0 = __builtin_amdgcn_mfma_i32_32x32x32_i8(a, b0, acc0, 0, 0, 0);
            acc1 = __builtin_amdgcn_mfma_i32_32x32x32_i8(a, b1, acc1, 0, 0, 0);
        }
    }

    #pragma unroll
    for (int g = 0; g < 16; ++g) {
        int o = om * 32 + (g & 3) + 8 * (g >> 2) + 4 * lk;
        float Ao = A[o], B0o = B0[o];
        float b2 = bias2[b * COUT + o], b3 = bias3[b * COUT + o], pa = prelu_a[o];
        const float* xr = x + ((size_t)(b * CIN + 2 * o)) * (HH * WW) + (size_t)h * WW;
        float* op = out + ((size_t)(b * COUT + o)) * (HH * WW) + (size_t)h * WW;
        {
            int w = lr;
            float cv = (float)acc0[g] * Ao + B0o;
            float r0 = xr[w], r1 = xr[HH * WW + w];
            float tv = cv + 0.5f * (r0 + r1) + b2;
            tv = tv > 0.f ? tv : pa * tv;
            op[w] = tv + b3;
        }
        {
            int w = 32 + lr;
            float cv = (float)acc1[g] * Ao + B0o;
            float r0 = xr[w], r1 = xr[HH * WW + w];
            float tv = cv + 0.5f * (r0 + r1) + b2;
            tv = tv > 0.f ? tv : pa * tv;
            op[w] = tv + b3;
        }
    }
}

extern "C" void kernel_launch(void* const* d_in, const int* in_sizes, int n_in,
                              void* d_out, int out_size, void* d_ws, size_t ws_size,
                              hipStream_t stream) {
    const float* x      = (const float*)d_in[0];
    const float* emb    = (const float*)d_in[1];
    const float* m1w    = (const float*)d_in[2];
    const float* m1b    = (const float*)d_in[3];
    const float* conv_w = (const float*)d_in[4];
    const float* conv_b = (const float*)d_in[5];
    const float* bn_g   = (const float*)d_in[6];
    const float* bn_b   = (const float*)d_in[7];
    const float* bn_m   = (const float*)d_in[8];
    const float* bn_v   = (const float*)d_in[9];
    const float* m2w    = (const float*)d_in[10];
    const float* m2b    = (const float*)d_in[11];
    const float* pa     = (const float*)d_in[12];
    const float* m3w    = (const float*)d_in[13];
    const float* m3b    = (const float*)d_in[14];
    float* out = (float*)d_out;

    char* ws = (char*)d_ws;
    float* bias1 = (float*)(ws + 0);
    float* bias2 = (float*)(ws + 16384);
    float* bias3 = (float*)(ws + 24576);
    float* Aarr  = (float*)(ws + 33280);
    float* B0arr = (float*)(ws + 33792);
    signed char* Wt = (signed char*)(ws + 34304);
    signed char* S  = (signed char*)(ws + 329216);

    prep2_k<<<256, 256, 0, stream>>>(emb, m1w, m1b, m2w, m2b, m3w, m3b,
                                     conv_w, conv_b, bn_g, bn_b, bn_m, bn_v,
                                     bias1, bias2, bias3, Aarr, B0arr, Wt);
    sign_k<<<BB * HH, 256, 0, stream>>>(x, bias1, S);
    main2_k<<<BB * HH, 256, 0, stream>>>(Wt, S, x, Aarr, B0arr,
                                         bias2, bias3, pa, out);
}